// Round 2
// baseline (2919.066 us; speedup 1.0000x reference)
//
#include <hip/hip_runtime.h>
#include <math.h>

#define TT 1024
#define U1 128
#define U2 32
#define G1 384
#define G2 96

__device__ __forceinline__ float rlf(float v, int lane) {
    return __int_as_float(__builtin_amdgcn_readlane(__float_as_int(v), lane));
}
__device__ __forceinline__ float fast_tanh(float v) {
    float e = __expf(2.f * v);      // v>>0: e=inf -> 1; v<<0: e=0 -> -1 (NaN-free)
    return 1.f - 2.f / (e + 1.f);
}
__device__ __forceinline__ float fast_sig(float v) {
    return 1.f / (1.f + __expf(-v));
}

// 256 blocks x 512 threads; block owns batches {2b, 2b+1}.
// Waves 0-5 (t 0..383): GRU1 dot role: col-pair {c, c+192}, u-half uh = t/192
//   (waves 0-2 -> uh0, waves 3-5 -> uh1: wave-uniform readlane indices).
//   h is loaded lane-distributed with ONE ds_read_b128/wave, then broadcast
//   via v_readlane -> SGPR -> FMA (no LDS in the inner loop).
// t 0..255 also: GRU1 unit-update role (unit j=t&127, batch b=t>>7); h_old in reg.
// t 320..383 also: GRU2 state update (lag-1), h2_old in reg.
// Waves 6-7 (t 384..511): GRU2 dot role (broadcast-LDS, small).
__global__ __launch_bounds__(512, 2)
void gru_stack_kernel(const float* __restrict__ x,   // [512,1024,1]
                      const float* __restrict__ k1,  // [1,384]
                      const float* __restrict__ rk1, // [128,384]
                      const float* __restrict__ b1,  // [2,384]
                      const float* __restrict__ k2,  // [128,96]
                      const float* __restrict__ rk2, // [32,96]
                      const float* __restrict__ b2,  // [2,96]
                      const float* __restrict__ wd,  // [32,1]
                      const float* __restrict__ bd,  // [1]
                      float* __restrict__ out)       // [512,1]
{
    __shared__ __align__(16) float h1s[2][U1];        // [b][u], 256 floats
    __shared__ __align__(16) float h2s[2][U2];
    __shared__ __align__(16) float part1[2][2][G1];   // [b][uh][gate]
    __shared__ __align__(16) float zr2s[2][2 * U2];
    __shared__ __align__(16) float ih2s[2][U2];
    __shared__ __align__(16) float xh2s[2][U2];

    const int t  = threadIdx.x;
    const int b0 = blockIdx.x * 2;

    if (t < 2 * U1) ((float*)h1s)[t] = 0.0f;
    if (t < 2 * U2) ((float*)h2s)[t] = 0.0f;

    if (t < G1) {
        // ---------------- GRU1 dot role ----------------
        const int c  = t % 192;
        const int uh = t / 192;     // wave-uniform (waves 0-2: 0, waves 3-5: 1)
        float w0[64], w1[64];
        {
            const float* rkp = rk1 + (uh * 64) * G1 + c;
#pragma unroll
            for (int j = 0; j < 64; ++j) {
                w0[j] = rkp[j * G1];
                w1[j] = rkp[j * G1 + 192];
            }
        }
        // ---------------- GRU1 update-role constants (t < 256) ----------------
        const int ju = t & 127, bu = t >> 7;
        float k1z = 0, k1r = 0, k1h = 0, bz = 0, br = 0, bhx = 0, bhr = 0;
        float h_old = 0.0f, h2_old = 0.0f;
        if (t < 256) {
            k1z = k1[ju]; k1r = k1[128 + ju]; k1h = k1[256 + ju];
            bz  = b1[ju]       + b1[G1 + ju];
            br  = b1[128 + ju] + b1[G1 + 128 + ju];
            bhx = b1[256 + ju];
            bhr = b1[G1 + 256 + ju];
        }
        __syncthreads();  // B0

        for (int i = 0; i <= TT; ++i) {
            float xv = 0.0f;
            if (t < 256 && i < TT) xv = x[(b0 + bu) * TT + i];

            if (i < TT) {
                float4 hv4 = ((const float4*)(const float*)h1s)[t & 63];
                float hvv[4] = {hv4.x, hv4.y, hv4.z, hv4.w};
                float a00 = 0.f, a01 = 0.f, a10 = 0.f, a11 = 0.f; // a[col][batch]
#define GRU1_DOT(BASE0, BASE1)                                   \
    _Pragma("unroll")                                            \
    for (int j = 0; j < 64; ++j) {                               \
        float s0 = rlf(hvv[j & 3], (BASE0) + (j >> 2));          \
        float s1 = rlf(hvv[j & 3], (BASE1) + (j >> 2));          \
        a00 = fmaf(s0, w0[j], a00);                              \
        a10 = fmaf(s0, w1[j], a10);                              \
        a01 = fmaf(s1, w0[j], a01);                              \
        a11 = fmaf(s1, w1[j], a11);                              \
    }
                if (uh == 0) { GRU1_DOT(0, 32) } else { GRU1_DOT(16, 48) }
#undef GRU1_DOT
                part1[0][uh][c]       = a00;
                part1[1][uh][c]       = a01;
                part1[0][uh][c + 192] = a10;
                part1[1][uh][c + 192] = a11;
            }
            __syncthreads();  // B1

            if (t < 256 && i < TT) {
                float iz = part1[bu][0][ju]       + part1[bu][1][ju];
                float ir = part1[bu][0][128 + ju] + part1[bu][1][128 + ju];
                float ih = part1[bu][0][256 + ju] + part1[bu][1][256 + ju];
                float z  = fmaxf(fmaf(xv, k1z, bz) + iz, 0.0f);   // rec_act=relu
                float r  = fmaxf(fmaf(xv, k1r, br) + ir, 0.0f);
                float hh = fast_tanh(fmaf(xv, k1h, bhx) + r * (ih + bhr));
                h_old = fmaf(z, h_old - hh, hh);
                h1s[bu][ju] = h_old;
            }
            if (t >= 320 && t < 384 && i >= 1) {
                const int tau = t - 320;
                const int b = tau >> 5, j = tau & 31;
                float z  = fast_sig(zr2s[b][j]);
                float r  = fast_sig(zr2s[b][U2 + j]);
                float hh = fmaxf(fmaf(r, ih2s[b][j], xh2s[b][j]), 0.0f);
                h2_old = fmaf(z, h2_old - hh, hh);
                h2s[b][j] = h2_old;
            }
            __syncthreads();  // B2
        }

        // ---------------- dense head ----------------
        if (t < 64) {
            const int b = t >> 5, j = t & 31;
            float p = h2s[b][j] * wd[j];
#pragma unroll
            for (int m = 16; m >= 1; m >>= 1) p += __shfl_xor(p, m, 64);
            if (j == 0) out[b0 + b] = p + bd[0];
        }
    } else {
        // ---------------- GRU2 dot role (t 384..511, 96 live) ----------------
        const int ggr   = t - G1;
        const bool live = ggr < G2;
        const int gg    = live ? ggr : (G2 - 1);
        float wk[U1];
#pragma unroll
        for (int u = 0; u < U1; ++u) wk[u] = k2[u * G2 + gg];
        float wr[U2];
#pragma unroll
        for (int u = 0; u < U2; ++u) wr[u] = rk2[u * G2 + gg];
        const float bin2  = b2[gg];
        const float brec2 = b2[G2 + gg];

        __syncthreads();  // B0

        for (int i = 0; i <= TT; ++i) {
            if (i >= 1) {
                // timestep i-1: uses h1(i-1) (seq1) and h2(i-2)
                float x0e = 0.f, x0o = 0.f, x1e = 0.f, x1o = 0.f;
                const float4* h40 = (const float4*)&h1s[0][0];
                const float4* h41 = (const float4*)&h1s[1][0];
#pragma unroll
                for (int u4 = 0; u4 < U1 / 4; ++u4) {
                    float4 a = h40[u4];
                    float4 c = h41[u4];
                    x0e = fmaf(a.x, wk[4 * u4 + 0], x0e);
                    x0o = fmaf(a.y, wk[4 * u4 + 1], x0o);
                    x0e = fmaf(a.z, wk[4 * u4 + 2], x0e);
                    x0o = fmaf(a.w, wk[4 * u4 + 3], x0o);
                    x1e = fmaf(c.x, wk[4 * u4 + 0], x1e);
                    x1o = fmaf(c.y, wk[4 * u4 + 1], x1o);
                    x1e = fmaf(c.z, wk[4 * u4 + 2], x1e);
                    x1o = fmaf(c.w, wk[4 * u4 + 3], x1o);
                }
                float r0 = 0.f, r1 = 0.f;
                const float4* g40 = (const float4*)&h2s[0][0];
                const float4* g41 = (const float4*)&h2s[1][0];
#pragma unroll
                for (int u4 = 0; u4 < U2 / 4; ++u4) {
                    float4 a = g40[u4];
                    float4 c = g41[u4];
                    r0 = fmaf(a.x, wr[4 * u4 + 0], r0);
                    r0 = fmaf(a.y, wr[4 * u4 + 1], r0);
                    r0 = fmaf(a.z, wr[4 * u4 + 2], r0);
                    r0 = fmaf(a.w, wr[4 * u4 + 3], r0);
                    r1 = fmaf(c.x, wr[4 * u4 + 0], r1);
                    r1 = fmaf(c.y, wr[4 * u4 + 1], r1);
                    r1 = fmaf(c.z, wr[4 * u4 + 2], r1);
                    r1 = fmaf(c.w, wr[4 * u4 + 3], r1);
                }
                float xp0 = (x0e + x0o) + bin2;
                float xp1 = (x1e + x1o) + bin2;
                float iv0 = r0 + brec2;
                float iv1 = r1 + brec2;
                if (live) {
                    if (gg < 2 * U2) {
                        zr2s[0][gg] = xp0 + iv0;
                        zr2s[1][gg] = xp1 + iv1;
                    } else {
                        ih2s[0][gg - 2 * U2] = iv0;
                        ih2s[1][gg - 2 * U2] = iv1;
                        xh2s[0][gg - 2 * U2] = xp0;
                        xh2s[1][gg - 2 * U2] = xp1;
                    }
                }
            }
            __syncthreads();  // B1
            __syncthreads();  // B2
        }
    }
}

extern "C" void kernel_launch(void* const* d_in, const int* in_sizes, int n_in,
                              void* d_out, int out_size, void* d_ws, size_t ws_size,
                              hipStream_t stream) {
    const float* x   = (const float*)d_in[0];
    const float* k1  = (const float*)d_in[1];
    const float* rk1 = (const float*)d_in[2];
    const float* b1  = (const float*)d_in[3];
    const float* k2  = (const float*)d_in[4];
    const float* rk2 = (const float*)d_in[5];
    const float* b2  = (const float*)d_in[6];
    const float* wd  = (const float*)d_in[7];
    const float* bd  = (const float*)d_in[8];
    float* out = (float*)d_out;

    dim3 grid(256), block(512);
    hipLaunchKernelGGL(gru_stack_kernel, grid, block, 0, stream,
                       x, k1, rk1, b1, k2, rk2, b2, wd, bd, out);
}

// Round 3
// 1194.147 us; speedup vs baseline: 2.4445x; 2.4445x over previous
//
#include <hip/hip_runtime.h>
#include <math.h>

#define TT 1024
#define U1 128
#define U2 32
#define NCOL 480   // 384 rk1 gate-cols + 96 k2 cols (both dot against h1)
#define NQ 120     // long-col quads
#define NUQ 4      // u-quarters

__device__ __forceinline__ float fast_tanh(float v) {
    float e = __expf(2.f * v);      // v>>0: e=inf -> 1; v<<0: e=0 -> -1 (NaN-free)
    return 1.f - 2.f / (e + 1.f);
}
__device__ __forceinline__ float fast_sig(float v) {
    return 1.f / (1.f + __expf(-v));
}

// 256 blocks x 512 threads; block owns batches {2b, 2b+1}; 1 block/CU.
// Dot phase (t<504, uniform branch-free loop): thread owns 4 consecutive
//   columns and a 32-long u-range; per float4 broadcast LDS read -> 16 FMAs.
//   t<480: cols 4q..4q+3 of [rk1|k2] vs h1 (u-quarter uq=t/120).
//   480<=t<504: cols of rk2 vs h2 (u=0..31 full).
// Update phase: t<256 GRU1 unit update (h_old in reg); t 256..319 GRU2
//   update lagged one step. 2 barriers/step.
__global__ __launch_bounds__(512, 1)
void gru_stack_kernel(const float* __restrict__ x,   // [512,1024,1]
                      const float* __restrict__ k1,  // [1,384]
                      const float* __restrict__ rk1, // [128,384]
                      const float* __restrict__ b1,  // [2,384]
                      const float* __restrict__ k2,  // [128,96]
                      const float* __restrict__ rk2, // [32,96]
                      const float* __restrict__ b2,  // [2,96]
                      const float* __restrict__ wd,  // [32,1]
                      const float* __restrict__ bd,  // [1]
                      float* __restrict__ out)       // [512,1]
{
    __shared__ __align__(16) float h1s[2][U1];
    __shared__ __align__(16) float h2s[2][U2];
    __shared__ __align__(16) float part1[2][NUQ][NCOL];  // [b][uq][col]
    __shared__ __align__(16) float part2[2][96];         // rk2 partials

    const int t  = threadIdx.x;
    const int b0 = blockIdx.x * 2;

    if (t < 2 * U1) ((float*)h1s)[t] = 0.f;
    if (t < 2 * U2) ((float*)h2s)[t] = 0.f;

    // ---------------- dot-role setup ----------------
    float4 w4[32];                      // 128 arch VGPRs: weights for 4 cols x 32 u
    const float4* pb0 = nullptr;        // h source, batch 0
    const float4* pb1 = nullptr;        // h source, batch 1
    float4* pd0 = nullptr;              // partial dest, batch 0
    float4* pd1 = nullptr;
    const bool is_dot = (t < 504);
    if (t < 480) {
        const int uq = t / NQ, q = t % NQ;
        const int c0 = 4 * q, ub = 32 * uq;
#pragma unroll
        for (int j = 0; j < 32; ++j) {
            const int u = ub + j;
            float vv[4];
#pragma unroll
            for (int r = 0; r < 4; ++r) {
                const int c = c0 + r;
                vv[r] = (c < 384) ? rk1[u * 384 + c] : k2[u * 96 + (c - 384)];
            }
            w4[j] = make_float4(vv[0], vv[1], vv[2], vv[3]);
        }
        pb0 = (const float4*)&h1s[0][ub];
        pb1 = (const float4*)&h1s[1][ub];
        pd0 = (float4*)&part1[0][uq][c0];
        pd1 = (float4*)&part1[1][uq][c0];
    } else if (t < 504) {
        const int q2 = t - 480, c0 = 4 * q2;
#pragma unroll
        for (int j = 0; j < 32; ++j)
            w4[j] = make_float4(rk2[j * 96 + c0 + 0], rk2[j * 96 + c0 + 1],
                                rk2[j * 96 + c0 + 2], rk2[j * 96 + c0 + 3]);
        pb0 = (const float4*)&h2s[0][0];
        pb1 = (const float4*)&h2s[1][0];
        pd0 = (float4*)&part2[0][c0];
        pd1 = (float4*)&part2[1][c0];
    }

    // ---------------- update-role setup ----------------
    const int ju = t & 127, bu = t >> 7;               // t<256: GRU1 update
    float k1z = 0, k1r = 0, k1h = 0, bz = 0, br = 0, bhx = 0, bhr = 0, h_old = 0;
    if (t < 256) {
        k1z = k1[ju]; k1r = k1[128 + ju]; k1h = k1[256 + ju];
        bz  = b1[ju]       + b1[384 + ju];
        br  = b1[128 + ju] + b1[384 + 128 + ju];
        bhx = b1[256 + ju];
        bhr = b1[384 + 256 + ju];
    }
    const int tau = t - 256, j2 = tau & 31, bb2 = tau >> 5;  // t 256..319: GRU2 update
    float bz2 = 0, br2 = 0, bh2x = 0, bh2r = 0, h2_old = 0;
    if (t >= 256 && t < 320) {
        bz2  = b2[j2]      + b2[96 + j2];
        br2  = b2[32 + j2] + b2[96 + 32 + j2];
        bh2x = b2[64 + j2];
        bh2r = b2[96 + 64 + j2];
    }

    __syncthreads();  // B0: h init visible

    for (int i = 0; i <= TT; ++i) {
        float xv = 0.f;
        if (t < 256 && i < TT) xv = x[(b0 + bu) * TT + i];

        if (is_dot) {
            float4 a0 = make_float4(0.f, 0.f, 0.f, 0.f);
            float4 a1 = make_float4(0.f, 0.f, 0.f, 0.f);
#pragma unroll
            for (int j4 = 0; j4 < 8; ++j4) {
                float4 hv0 = pb0[j4];
                float4 hv1 = pb1[j4];
                float ha0[4] = {hv0.x, hv0.y, hv0.z, hv0.w};
                float ha1[4] = {hv1.x, hv1.y, hv1.z, hv1.w};
#pragma unroll
                for (int e = 0; e < 4; ++e) {
                    const float4 wv = w4[4 * j4 + e];
                    const float he0 = ha0[e], he1 = ha1[e];
                    a0.x = fmaf(he0, wv.x, a0.x);
                    a0.y = fmaf(he0, wv.y, a0.y);
                    a0.z = fmaf(he0, wv.z, a0.z);
                    a0.w = fmaf(he0, wv.w, a0.w);
                    a1.x = fmaf(he1, wv.x, a1.x);
                    a1.y = fmaf(he1, wv.y, a1.y);
                    a1.z = fmaf(he1, wv.z, a1.z);
                    a1.w = fmaf(he1, wv.w, a1.w);
                }
            }
            *pd0 = a0;
            *pd1 = a1;
        }
        __syncthreads();  // B1: partials visible

        if (t < 256 && i < TT) {
            // GRU1 unit update: z/r = relu, hh = tanh (reset_after)
            float iz = part1[bu][0][ju] + part1[bu][1][ju]
                     + part1[bu][2][ju] + part1[bu][3][ju];
            float ir = part1[bu][0][128 + ju] + part1[bu][1][128 + ju]
                     + part1[bu][2][128 + ju] + part1[bu][3][128 + ju];
            float ih = part1[bu][0][256 + ju] + part1[bu][1][256 + ju]
                     + part1[bu][2][256 + ju] + part1[bu][3][256 + ju];
            float z  = fmaxf(fmaf(xv, k1z, bz) + iz, 0.f);
            float r  = fmaxf(fmaf(xv, k1r, br) + ir, 0.f);
            float hh = fast_tanh(fmaf(xv, k1h, bhx) + r * (ih + bhr));
            h_old = fmaf(z, h_old - hh, hh);
            h1s[bu][ju] = h_old;
        } else if (t >= 256 && t < 320 && i >= 1) {
            // GRU2 unit update (one step behind): z/r = sigmoid, hh = relu
            float xz = part1[bb2][0][384 + j2] + part1[bb2][1][384 + j2]
                     + part1[bb2][2][384 + j2] + part1[bb2][3][384 + j2];
            float xr = part1[bb2][0][416 + j2] + part1[bb2][1][416 + j2]
                     + part1[bb2][2][416 + j2] + part1[bb2][3][416 + j2];
            float xh = part1[bb2][0][448 + j2] + part1[bb2][1][448 + j2]
                     + part1[bb2][2][448 + j2] + part1[bb2][3][448 + j2];
            float iz = part2[bb2][j2];
            float ir = part2[bb2][32 + j2];
            float ih = part2[bb2][64 + j2];
            float z  = fast_sig(xz + iz + bz2);
            float r  = fast_sig(xr + ir + br2);
            float hh = fmaxf(xh + bh2x + r * (ih + bh2r), 0.f);
            h2_old = fmaf(z, h2_old - hh, hh);
            h2s[bb2][j2] = h2_old;
        }
        __syncthreads();  // B2: h updated
    }

    // ---------------- dense head ----------------
    if (t < 64) {
        const int b = t >> 5, j = t & 31;
        float p = h2s[b][j] * wd[j];
#pragma unroll
        for (int m = 16; m >= 1; m >>= 1) p += __shfl_xor(p, m, 64);
        if (j == 0) out[b0 + b] = p + bd[0];
    }
}

extern "C" void kernel_launch(void* const* d_in, const int* in_sizes, int n_in,
                              void* d_out, int out_size, void* d_ws, size_t ws_size,
                              hipStream_t stream) {
    const float* x   = (const float*)d_in[0];
    const float* k1  = (const float*)d_in[1];
    const float* rk1 = (const float*)d_in[2];
    const float* b1  = (const float*)d_in[3];
    const float* k2  = (const float*)d_in[4];
    const float* rk2 = (const float*)d_in[5];
    const float* b2  = (const float*)d_in[6];
    const float* wd  = (const float*)d_in[7];
    const float* bd  = (const float*)d_in[8];
    float* out = (float*)d_out;

    dim3 grid(256), block(512);
    hipLaunchKernelGGL(gru_stack_kernel, grid, block, 0, stream,
                       x, k1, rk1, b1, k2, rk2, b2, wd, bd, out);
}